// Round 2
// baseline (1318.492 us; speedup 1.0000x reference)
//
#include <hip/hip_runtime.h>

// Problem constants
#define NK 19                 // classes
#define NC 64                 // channels
#define HW (512*512)          // pixels per (batch, channel) plane
#define BLOCK 256
#define PIX_PER_BLOCK 1024    // pixels per block
#define NTILES 16             // 16 tiles of 64 pixels each
#define NBLOCKS 2048          // 8 batches * 256 chunks
#define NCOPIES 16            // rotating global accumulator copies
#define SUMS (NK*NC)          // 1216
#define COPY_STRIDE 1280      // floats per copy: 1216 sums + 19 counts + pad
#define TROW 65               // padded tile row stride (floats) -> bank spread

// ---------------------------------------------------------------------------
// Kernel 1: transpose tiles through LDS so lane = channel, making the class
// scatter (ds_add_f32) nearly conflict-free (same-address multiplicity <= 4,
// typically 1; ~2-way bank aliasing which is free on gfx950).
// ---------------------------------------------------------------------------
__global__ __launch_bounds__(BLOCK) void accum_kernel(
    const float* __restrict__ x, const int* __restrict__ t,
    float* __restrict__ ws) {
  __shared__ float tile[NC * TROW];      // 64 x 65 floats = 16.6 KB
  __shared__ float bins[SUMS];           // [c][k], block-level
  __shared__ int   lbl[PIX_PER_BLOCK];   // 1024 labels, 4 KB
  __shared__ float cnt[8][NK];           // 8-way sub-binned counts

  const int tid = threadIdx.x;
  const int bid = blockIdx.x;
  const int batch   = bid >> 8;
  const int pixbase = (bid & 255) << 10;

  // zero accumulators
  for (int i = tid; i < SUMS; i += BLOCK) bins[i] = 0.0f;
  if (tid < 8 * NK) ((float*)cnt)[tid] = 0.0f;
  __syncthreads();

  // stage labels (coalesced int4) + count them (sub-binned: max ~2-way addr dup)
  {
    const int4 l4 = *reinterpret_cast<const int4*>(
        t + (size_t)batch * HW + pixbase + tid * 4);
    *reinterpret_cast<int4*>(&lbl[tid * 4]) = l4;
    float* cr = cnt[tid & 7];
    atomicAdd(cr + l4.x, 1.0f);
    atomicAdd(cr + l4.y, 1.0f);
    atomicAdd(cr + l4.z, 1.0f);
    atomicAdd(cr + l4.w, 1.0f);
  }
  // visibility of lbl/bins/cnt is covered by the first in-loop barrier

  // staging role: thread -> (row r = channel, slot s); 4 float4 per thread,
  // each wave-instr covers 16 rows x 64B contiguous segments (coalesced)
  const int r = tid >> 2;
  const int s = tid & 3;
  const float* xrow = x + (size_t)(batch * NC + r) * HW + pixbase;
  float* tdst = &tile[r * TROW];

  // processing role: lane -> (channel my_c, pixel-quarter pg)
  const int wv = tid >> 6;
  const int ln = tid & 63;
  const int my_c = wv * 16 + (ln & 15);
  const int pg = ln >> 4;
  float* bc = &bins[my_c * NK];

  for (int tl = 0; tl < NTILES; ++tl) {
    // issue staging loads BEFORE the barrier: overlaps previous tile's compute
    const float* src = xrow + tl * 64 + s * 4;
    const float4 v0 = *reinterpret_cast<const float4*>(src + 0);
    const float4 v1 = *reinterpret_cast<const float4*>(src + 16);
    const float4 v2 = *reinterpret_cast<const float4*>(src + 32);
    const float4 v3 = *reinterpret_cast<const float4*>(src + 48);
    __syncthreads();   // previous tile fully consumed
    float* dst = tdst + s * 4;
    *reinterpret_cast<float4*>(dst + 0)  = v0;
    *reinterpret_cast<float4*>(dst + 16) = v1;
    *reinterpret_cast<float4*>(dst + 32) = v2;
    *reinterpret_cast<float4*>(dst + 48) = v3;
    __syncthreads();   // tile visible

    // lane = channel: scatter 16 pixels of my_c into bins[my_c*19 + t]
    const float* trow = &tile[my_c * TROW + pg * 16];
    const int*   lrow = &lbl[tl * 64 + pg * 16];
#pragma unroll
    for (int j = 0; j < 4; ++j) {
      const float4 xv = *reinterpret_cast<const float4*>(trow + j * 4);
      const int4   t4 = *reinterpret_cast<const int4*>(lrow + j * 4);
      atomicAdd(bc + t4.x, xv.x);
      atomicAdd(bc + t4.y, xv.y);
      atomicAdd(bc + t4.z, xv.z);
      atomicAdd(bc + t4.w, xv.w);
    }
  }

  __syncthreads();

  // flush block sums + counts to one of 16 rotating global copies
  float* base = ws + (size_t)(bid & (NCOPIES - 1)) * COPY_STRIDE;
  for (int i = tid; i < SUMS; i += BLOCK) atomicAdd(base + i, bins[i]);
  if (tid < NK) {
    float sc = 0.0f;
    for (int rr = 0; rr < 8; ++rr) sc += cnt[rr][tid];
    atomicAdd(base + SUMS + tid, sc);
  }
}

// ---------------------------------------------------------------------------
// Kernel 2: centers -> norms -> 19x19 cosine pairs -> scalar loss
// ---------------------------------------------------------------------------
__global__ __launch_bounds__(512) void finalize_kernel(
    const float* __restrict__ ws, float* __restrict__ out) {
  __shared__ float cen[NC * 20];   // [c][k], padded to 20 for bank spread
  __shared__ float invn[NK];
  __shared__ float cc[NK];
  __shared__ float red[8];

  const int tid = threadIdx.x;

  if (tid < NK) {
    float s = 0.0f;
    for (int r = 0; r < NCOPIES; ++r) s += ws[r * COPY_STRIDE + SUMS + tid];
    cc[tid] = fmaxf(s, 1.0f);
  }
  __syncthreads();

  for (int i = tid; i < SUMS; i += 512) {
    int c = i / NK, k = i - c * NK;
    float s = 0.0f;
    for (int r = 0; r < NCOPIES; ++r) s += ws[r * COPY_STRIDE + i];
    cen[c * 20 + k] = s / cc[k];
  }
  __syncthreads();

  if (tid < NK) {
    float sq = 0.0f;
    for (int c = 0; c < NC; ++c) {
      float v = cen[c * 20 + tid];
      sq += v * v;
    }
    invn[tid] = 1.0f / fmaxf(sqrtf(sq), 1e-8f);
  }
  __syncthreads();

  float contrib = 0.0f;
  if (tid < NK * NK) {
    int i = tid / NK, j = tid - (tid / NK) * NK;
    float dot = 0.0f;
    for (int c = 0; c < NC; ++c) dot += cen[c * 20 + i] * cen[c * 20 + j];
    float S = dot * invn[i] * invn[j];
    contrib = (i == j) ? (1.0f - S) : fmaxf(S, 0.0f);
  }

  for (int off = 32; off > 0; off >>= 1) contrib += __shfl_down(contrib, off, 64);
  if ((tid & 63) == 0) red[tid >> 6] = contrib;
  __syncthreads();
  if (tid == 0) {
    float s = 0.0f;
    for (int w = 0; w < 8; ++w) s += red[w];
    out[0] = s / 6859.0f;  // / K^3
  }
}

extern "C" void kernel_launch(void* const* d_in, const int* in_sizes, int n_in,
                              void* d_out, int out_size, void* d_ws, size_t ws_size,
                              hipStream_t stream) {
  const float* x = (const float*)d_in[0];
  const int*   t = (const int*)d_in[1];
  float* ws = (float*)d_ws;

  hipMemsetAsync(d_ws, 0, (size_t)NCOPIES * COPY_STRIDE * sizeof(float), stream);
  accum_kernel<<<NBLOCKS, BLOCK, 0, stream>>>(x, t, ws);
  finalize_kernel<<<1, 512, 0, stream>>>(ws, (float*)d_out);
}

// Round 3
// 994.240 us; speedup vs baseline: 1.3261x; 1.3261x over previous
//
#include <hip/hip_runtime.h>

#define NK 19
#define NC 64
#define HW (512*512)
#define BLOCK 256
#define PPB 1024            // pixels per block
#define NTILES 16
#define TPIX 64             // pixels per tile
#define TROW 66             // padded LDS row stride: bank=(2c+p)&31 -> <=2-way (free)
#define NBLOCKS 2048
#define SUMS (NK*NC)        // 1216
#define MAXCOPIES 64

// ---------------------------------------------------------------------------
// Kernel 1: per-class feature sums WITHOUT per-element atomics.
// Lane owns 4 channels {cb, cb+16, cb+32, cb+48}; label shared across them ->
// one compare serves 4 FMAs into register accumulators acc[19][4].
// ---------------------------------------------------------------------------
__global__ __launch_bounds__(BLOCK) void accum_kernel(
    const float* __restrict__ x, const int* __restrict__ t,
    float* __restrict__ ws, int copymask) {
  __shared__ float tile[NC * TROW];   // 16.9 KB
  __shared__ int   lbl[PPB];          // 4 KB
  __shared__ float bins[4][SUMS];     // 19.5 KB per-wave partials

  const int tid = threadIdx.x;
  const int bid = blockIdx.x;
  const int batch   = bid >> 8;
  const int pixbase = (bid & 255) << 10;

  // stage labels once (coalesced int4)
  {
    const int4 l4 = *reinterpret_cast<const int4*>(
        t + (size_t)batch * HW + pixbase + tid * 4);
    *reinterpret_cast<int4*>(&lbl[tid * 4]) = l4;
  }

  // staging role: thread -> (row r = channel, slot s)
  const int r = tid >> 2, s = tid & 3;
  const float* xrow = x + (size_t)(batch * NC + r) * HW + pixbase;
  float* tdst = &tile[r * TROW + s * 4];

  // compute role: lane -> channel-base cb (4 channels), pixel-subgroup pg
  const int wv = tid >> 6, ln = tid & 63;
  const int cb = ln & 15, pg = ln >> 4;

  float acc[NK][4];
#pragma unroll
  for (int k = 0; k < NK; ++k) {
#pragma unroll
    for (int j = 0; j < 4; ++j) acc[k][j] = 0.0f;
  }

  for (int tl = 0; tl < NTILES; ++tl) {
    // prefetch BEFORE barrier: overlaps previous tile's compute
    const float* src = xrow + tl * TPIX + s * 4;
    const float4 a0 = *reinterpret_cast<const float4*>(src + 0);
    const float4 a1 = *reinterpret_cast<const float4*>(src + 16);
    const float4 a2 = *reinterpret_cast<const float4*>(src + 32);
    const float4 a3 = *reinterpret_cast<const float4*>(src + 48);
    __syncthreads();   // previous tile fully consumed
    *reinterpret_cast<float4*>(tdst + 0)  = a0;
    *reinterpret_cast<float4*>(tdst + 16) = a1;
    *reinterpret_cast<float4*>(tdst + 32) = a2;
    *reinterpret_cast<float4*>(tdst + 48) = a3;
    __syncthreads();   // tile visible

    const int pb = wv * 16;          // wave's 16 pixels within the tile
#pragma unroll
    for (int i = 0; i < 4; ++i) {
      const int p = pb + i * 4 + pg; // pg-interleaved -> 2-way banks (free)
      const int lab = lbl[tl * TPIX + p];
      const float v0 = tile[(cb +  0) * TROW + p];
      const float v1 = tile[(cb + 16) * TROW + p];
      const float v2 = tile[(cb + 32) * TROW + p];
      const float v3 = tile[(cb + 48) * TROW + p];
#pragma unroll
      for (int k = 0; k < NK; ++k) {
        const float sel = (lab == k) ? 1.0f : 0.0f;
        acc[k][0] = fmaf(v0, sel, acc[k][0]);
        acc[k][1] = fmaf(v1, sel, acc[k][1]);
        acc[k][2] = fmaf(v2, sel, acc[k][2]);
        acc[k][3] = fmaf(v3, sel, acc[k][3]);
      }
    }
  }

  // reduce across the 4 pg-lanes that share channels (xor bits 4,5)
#pragma unroll
  for (int k = 0; k < NK; ++k) {
#pragma unroll
    for (int j = 0; j < 4; ++j) {
      float v = acc[k][j];
      v += __shfl_xor(v, 16, 64);
      v += __shfl_xor(v, 32, 64);
      acc[k][j] = v;
    }
  }
  if (pg == 0) {
#pragma unroll
    for (int k = 0; k < NK; ++k) {
#pragma unroll
      for (int j = 0; j < 4; ++j)
        bins[wv][k * NC + cb + 16 * j] = acc[k][j];
    }
  }
  __syncthreads();

  // block flush: sum 4 wave slices, native fp32 global atomic (no CAS)
  float* base = ws + (size_t)(bid & copymask) * SUMS;
  for (int i = tid; i < SUMS; i += BLOCK) {
    float v = bins[0][i] + bins[1][i] + bins[2][i] + bins[3][i];
    unsafeAtomicAdd(base + i, v);
  }
}

// ---------------------------------------------------------------------------
// Kernel 2: label histogram in registers (no per-element atomics)
// ---------------------------------------------------------------------------
__global__ __launch_bounds__(BLOCK) void hist_kernel(
    const int* __restrict__ t, float* __restrict__ cnts) {
  int cnt[NK];
#pragma unroll
  for (int k = 0; k < NK; ++k) cnt[k] = 0;
  const int tid = threadIdx.x;
  const size_t base = (size_t)blockIdx.x * 8192;
#pragma unroll
  for (int q = 0; q < 8; ++q) {
    const int4 l4 = *reinterpret_cast<const int4*>(t + base + q * 1024 + tid * 4);
#pragma unroll
    for (int k = 0; k < NK; ++k)
      cnt[k] += (l4.x == k) + (l4.y == k) + (l4.z == k) + (l4.w == k);
  }
#pragma unroll
  for (int k = 0; k < NK; ++k) {
    int v = cnt[k];
    v += __shfl_xor(v, 1, 64);  v += __shfl_xor(v, 2, 64);
    v += __shfl_xor(v, 4, 64);  v += __shfl_xor(v, 8, 64);
    v += __shfl_xor(v, 16, 64); v += __shfl_xor(v, 32, 64);
    cnt[k] = v;
  }
  if ((tid & 63) == 0) {
#pragma unroll
    for (int k = 0; k < NK; ++k)
      unsafeAtomicAdd(cnts + k, (float)cnt[k]);
  }
}

// ---------------------------------------------------------------------------
// Kernel 3: reduce copies -> centers -> norms -> 19x19 cosine -> scalar
// ---------------------------------------------------------------------------
__global__ __launch_bounds__(512) void finalize_kernel(
    const float* __restrict__ ws, const float* __restrict__ cnts,
    float* __restrict__ out, int ncopies) {
  __shared__ float cen[SUMS];   // [k*64 + c]
  __shared__ float invn[NK];
  __shared__ float cc[NK];
  __shared__ float red[8];

  const int tid = threadIdx.x;
  if (tid < NK) cc[tid] = fmaxf(cnts[tid], 1.0f);
  __syncthreads();

  for (int i = tid; i < SUMS; i += 512) {
    float s = 0.0f;
    for (int r = 0; r < ncopies; ++r) s += ws[(size_t)r * SUMS + i];
    cen[i] = s / cc[i >> 6];
  }
  __syncthreads();

  if (tid < NK) {
    float sq = 0.0f;
    for (int c = 0; c < NC; ++c) { float v = cen[tid * NC + c]; sq += v * v; }
    invn[tid] = 1.0f / fmaxf(sqrtf(sq), 1e-8f);
  }
  __syncthreads();

  float contrib = 0.0f;
  if (tid < NK * NK) {
    int i = tid / NK, j = tid - (tid / NK) * NK;
    float dot = 0.0f;
    for (int c = 0; c < NC; ++c) dot += cen[i * NC + c] * cen[j * NC + c];
    float S = dot * invn[i] * invn[j];
    contrib = (i == j) ? (1.0f - S) : fmaxf(S, 0.0f);
  }
  for (int off = 32; off > 0; off >>= 1) contrib += __shfl_down(contrib, off, 64);
  if ((tid & 63) == 0) red[tid >> 6] = contrib;
  __syncthreads();
  if (tid == 0) {
    float s = 0.0f;
    for (int w = 0; w < 8; ++w) s += red[w];
    out[0] = s / 6859.0f;  // / K^3
  }
}

extern "C" void kernel_launch(void* const* d_in, const int* in_sizes, int n_in,
                              void* d_out, int out_size, void* d_ws, size_t ws_size,
                              hipStream_t stream) {
  const float* x = (const float*)d_in[0];
  const int*   t = (const int*)d_in[1];
  float* ws = (float*)d_ws;

  // as many power-of-2 rotating copies as the workspace allows (<=64)
  int ncopies = 1;
  while (ncopies < MAXCOPIES &&
         (size_t)(ncopies * 2 * SUMS + 32) * sizeof(float) <= ws_size)
    ncopies *= 2;
  float* cnts = ws + (size_t)ncopies * SUMS;

  hipMemsetAsync(d_ws, 0, ((size_t)ncopies * SUMS + 32) * sizeof(float), stream);
  accum_kernel<<<NBLOCKS, BLOCK, 0, stream>>>(x, t, ws, ncopies - 1);
  hist_kernel<<<256, BLOCK, 0, stream>>>(t, cnts);
  finalize_kernel<<<1, 512, 0, stream>>>(ws, cnts, (float*)d_out, ncopies);
}